// Round 1
// 152.039 us; speedup vs baseline: 1.0262x; 1.0262x over previous
//
#include <hip/hip_runtime.h>
#include <math.h>

#define BN 4096
#define DIM 256
#define D4 (DIM/4)        // 64 float4 per row
#define MI 8              // anchors per workgroup (fallback k_main)
#define MARGINF 0.3f
#define EPSF 1e-6f
#define SCAP 96           // staged class-member rows in k_pos (fallback)
#define IMAX 0x7fffffff
#define PCAP 512          // member-list capacity in k_posm (max class size ~90 here)

typedef __attribute__((ext_vector_type(8))) short bf16x8;
typedef __attribute__((ext_vector_type(4))) float f32x4;

__device__ __forceinline__ float fma4(float4 a, float4 b, float c){
  return fmaf(a.x,b.x, fmaf(a.y,b.y, fmaf(a.z,b.z, fmaf(a.w,b.w, c))));
}
__device__ __forceinline__ unsigned short f2bf(float x){   // RNE fp32 -> bf16
  unsigned u = __float_as_uint(x);
  return (unsigned short)((u + 0x7FFFu + ((u>>16)&1u)) >> 16);
}
__device__ __forceinline__ float bf2f(unsigned short h){
  return __uint_as_float(((unsigned)h)<<16);
}

// ------- kernel A: E -> EhiT/EloT fragment-tiled + per-row sq (256 blocks) ---
// Tiled layout (16B units): idx16 = g*512 + kk*64 + lane, holding row
// g*16+(lane&15), k-elements kk*32+(lane>>4)*8 .. +8.  One group per block.
__global__ __launch_bounds__(256) void k_pre2(const float* __restrict__ E,
     unsigned short* __restrict__ EhiT, unsigned short* __restrict__ EloT,
     float* __restrict__ sq, unsigned int* __restrict__ counter){
  int t = threadIdx.x;
  int g = blockIdx.x;                 // 256 blocks: group g = rows g*16..+15
  const float4* E4 = (const float4*)E;
  bf16x8* HT = (bf16x8*)EhiT;
  bf16x8* LT = (bf16x8*)EloT;
  #pragma unroll
  for (int it=0; it<2; it++){
    int idx = it*256 + t;             // 0..511 = kk*64 + sub
    int kk = idx>>6, sub = idx&63, q = sub>>4, n = sub&15;
    int r = g*16 + n;
    int c = kk*4 + q;                 // 16B chunk pair within row
    float4 v0 = E4[(size_t)r*64 + c*2];
    float4 v1 = E4[(size_t)r*64 + c*2 + 1];
    unsigned short h[8], lo[8];
    float vv[8] = {v0.x,v0.y,v0.z,v0.w, v1.x,v1.y,v1.z,v1.w};
    #pragma unroll
    for (int i=0;i<8;i++){ h[i]=f2bf(vv[i]); lo[i]=f2bf(vv[i]-bf2f(h[i])); }
    bf16x8 hv, lv;
    #pragma unroll
    for (int i=0;i<8;i++){ hv[i]=(short)h[i]; lv[i]=(short)lo[i]; }
    size_t d = (size_t)g*512 + idx;   // lane-consecutive writes
    HT[d] = hv; LT[d] = lv;
  }
  // per-row squared norm: 16 lanes per row
  int row = t>>4, part = t&15;
  const float4* rp = E4 + (size_t)(g*16+row)*64 + part*4;
  float s0 = fma4(rp[0],rp[0],0.f);
  float s1 = fma4(rp[1],rp[1],0.f);
  s0 = fma4(rp[2],rp[2],s0);
  s1 = fma4(rp[3],rp[3],s1);
  float s = s0+s1;
  s += __shfl_xor(s,1); s += __shfl_xor(s,2); s += __shfl_xor(s,4); s += __shfl_xor(s,8);
  if (part==0) sq[g*16+row] = s;
  if (g==0 && t==0) counter[0] = 0u;
}

// ------- kernel B: hardest positive per anchor (wave-per-anchor, fp32 exact) --
// 1024 blocks x 256 thr (4 waves). Member list via ballot+prefix-popcount, then
// 4-way ILP batches (4 independent shuffle-reduce chains). Same fp32 math and
// reduce order as the previous fused phase-1 -> identical ap/hp.
// Also initializes the atomic merge cells for k_negm.
__global__ __launch_bounds__(256) void k_posm(const float* __restrict__ E,
     const int* __restrict__ labels, const float* __restrict__ sq,
     float* __restrict__ apw, int* __restrict__ hpw,
     unsigned long long* __restrict__ negKey, unsigned int* __restrict__ semiJ){
  __shared__ __align__(16) int   labsS[BN];    // 16 KB
  __shared__ __align__(16) float sqS[BN];      // 16 KB
  __shared__ int mem[4][PCAP+4];               // 8.06 KB, per-wave member lists
  int t=threadIdx.x, l=t&63, w=t>>6;
  #pragma unroll
  for (int i=0;i<4;i++){
    ((int4*)labsS)[i*256+t]   = ((const int4*)labels)[i*256+t];
    ((float4*)sqS)[i*256+t]   = ((const float4*)sq)[i*256+t];
  }
  __syncthreads();
  int aw = blockIdx.x*4 + w;
  int labW = labsS[aw];
  float sqw_ = sqS[aw];
  const float4* E4 = (const float4*)E;
  float4 areg = E4[(size_t)aw*64 + l];          // lane l: dims 4l..4l+3
  // build ascending member list
  int cnt = 0;
  for (int c=0;c<64;c++){
    int j = c*64 + l;
    bool m = (labsS[j]==labW) && (j != aw);
    unsigned long long mask = __ballot(m);
    if (m){
      int pos = cnt + __popcll(mask & ((1ull<<l)-1ull));
      if (pos < PCAP) mem[w][pos] = j;
    }
    cnt += __popcll(mask);
  }
  if (cnt > PCAP) cnt = PCAP;
  if (l < 4) mem[w][cnt + l] = aw;              // pad (masked by validity checks)
  // scan in batches of 4 (independent chains -> ILP)
  float bv2 = -INFINITY; int bj = IMAX;
  for (int base=0; base<cnt; base+=4){
    int j0=mem[w][base+0], j1=mem[w][base+1], j2=mem[w][base+2], j3=mem[w][base+3];
    float4 r0=E4[(size_t)j0*64+l];
    float4 r1=E4[(size_t)j1*64+l];
    float4 r2=E4[(size_t)j2*64+l];
    float4 r3=E4[(size_t)j3*64+l];
    float p0=fma4(areg,r0,0.f), p1=fma4(areg,r1,0.f);
    float p2=fma4(areg,r2,0.f), p3=fma4(areg,r3,0.f);
    #pragma unroll
    for (int off=32; off; off>>=1){
      p0 += __shfl_xor(p0,off); p1 += __shfl_xor(p1,off);
      p2 += __shfl_xor(p2,off); p3 += __shfl_xor(p3,off);
    }
    float d0 = sqw_ + sqS[j0] - 2.0f*p0;
    float d1 = sqw_ + sqS[j1] - 2.0f*p1;
    float d2 = sqw_ + sqS[j2] - 2.0f*p2;
    float d3 = sqw_ + sqS[j3] - 2.0f*p3;
    if (d0 > bv2){ bv2=d0; bj=j0; }                      // ascending j: first max
    if (base+1<cnt && d1 > bv2){ bv2=d1; bj=j1; }
    if (base+2<cnt && d2 > bv2){ bv2=d2; bj=j2; }
    if (base+3<cnt && d3 > bv2){ bv2=d3; bj=j3; }
  }
  if (l==0){
    apw[aw] = (bj==IMAX) ? -INFINITY : sqrtf(fmaxf(bv2, 0.0f)); // -inf => no positive
    hpw[aw] = (bj==IMAX) ? 0 : bj;
    negKey[aw] = ~0ull;                 // init atomic merge cells for k_negm
    semiJ[aw]  = 0xFFFFFFFFu;
  }
}

// ------- kernel C: split-bf16 MFMA pass, MT=32 anchors x 2048-col half --------
// grid 256 = 128 anchor-groups x 2 column halves (XCD-swizzled so each XCD
// keeps one 2MB B-half L2-resident). d^2-space selection identical to before.
// Halves merge deterministically via atomicMin on order-encoded (d2,j) keys.
__global__ __launch_bounds__(1024,4) void k_negm(
     const unsigned short* __restrict__ EhiT, const unsigned short* __restrict__ EloT,
     const int* __restrict__ labels, const float* __restrict__ sq,
     const float* __restrict__ apw,
     unsigned long long* __restrict__ negKey, unsigned int* __restrict__ semiJ){
  __shared__ bf16x8 afH[1024];        // 16 KB  A-hi fragments (2 groups of 16 rows)
  __shared__ bf16x8 afL[1024];        // 16 KB  A-lo fragments
  __shared__ __align__(16) int   labsH[2048];  // 8 KB  labels of this col-half
  __shared__ __align__(16) float sqH[2048];    // 8 KB
  __shared__ float rnv[16][32]; __shared__ int rnj[16][32]; __shared__ int rsm[16][32];
  int t=threadIdx.x, l=t&63, w=t>>6;
  int lane16 = l&15, quad = l>>4;
  int q8   = blockIdx.x & 7;          // XCD-aware: XCDs 0-3 -> half 0, 4-7 -> half 1
  int half = q8 >> 2;
  int grp  = (blockIdx.x >> 3)*4 + (q8 & 3);   // 0..127
  int a0 = grp*32;
  int hbase = half*2048;
  const bf16x8* HT = (const bf16x8*)EhiT;
  const bf16x8* LT = (const bf16x8*)EloT;
  // stage A fragments (two 16-row groups) + half's labels/sq (all coalesced)
  afH[t] = HT[(size_t)grp*1024 + t];
  afL[t] = LT[(size_t)grp*1024 + t];
  { int2   lv = ((const int2*)(labels + hbase))[t];
    labsH[2*t] = lv.x; labsH[2*t+1] = lv.y;
    float2 sv = ((const float2*)(sq + hbase))[t];
    sqH[2*t] = sv.x; sqH[2*t+1] = sv.y; }
  // per-thread anchor metadata: 8 anchors (g=0,1 ; r=0..3), anchor row quad*4+r
  float sqa[2][4]; int laba[2][4]; float ap2[2][4]; float th2[2][4];
  #pragma unroll
  for (int g=0; g<2; g++){
    #pragma unroll
    for (int r=0; r<4; r++){
      int ag = a0 + g*16 + quad*4 + r;
      sqa[g][r] = sq[ag]; laba[g][r] = labels[ag];
      float ap = apw[ag];
      ap2[g][r] = ap*ap;                 // ap=-inf => ap2=+inf => empty window
      float th = ap + MARGINF;
      th2[g][r] = th*th;
    }
  }
  __syncthreads();
  float mn[2][4]; int mj[2][4]; int sm[2][4];
  #pragma unroll
  for (int g=0; g<2; g++)
    #pragma unroll
    for (int r=0; r<4; r++){ mn[g][r]=INFINITY; mj[g][r]=IMAX; sm[g][r]=IMAX; }
  #pragma unroll 1
  for (int tile=0; tile<8; tile++){
    int gl = w*8 + tile;                         // local col-group 0..127
    size_t BBase = (size_t)(half*128 + gl) * 512;
    f32x4 acc00={0.f,0.f,0.f,0.f}, acc01=acc00, acc02=acc00;
    f32x4 acc10=acc00, acc11=acc00, acc12=acc00;
    #pragma unroll 2
    for (int kk=0; kk<8; kk++){
      bf16x8 bh  = HT[BBase + kk*64 + l];        // global, lane-consecutive 1KB
      bf16x8 bl  = LT[BBase + kk*64 + l];
      bf16x8 ah0 = afH[kk*64 + l];               // LDS b128, conflict-free
      bf16x8 al0 = afL[kk*64 + l];
      bf16x8 ah1 = afH[512 + kk*64 + l];
      bf16x8 al1 = afL[512 + kk*64 + l];
      acc00 = __builtin_amdgcn_mfma_f32_16x16x32_bf16(ah0, bh, acc00, 0,0,0);
      acc01 = __builtin_amdgcn_mfma_f32_16x16x32_bf16(ah0, bl, acc01, 0,0,0);
      acc02 = __builtin_amdgcn_mfma_f32_16x16x32_bf16(al0, bh, acc02, 0,0,0);
      acc10 = __builtin_amdgcn_mfma_f32_16x16x32_bf16(ah1, bh, acc10, 0,0,0);
      acc11 = __builtin_amdgcn_mfma_f32_16x16x32_bf16(ah1, bl, acc11, 0,0,0);
      acc12 = __builtin_amdgcn_mfma_f32_16x16x32_bf16(al1, bh, acc12, 0,0,0);
    }
    int jloc = gl*16 + lane16;
    int lj = labsH[jloc]; float sqj = sqH[jloc];
    int jglob = hbase + jloc;
    #pragma unroll
    for (int r=0; r<4; r++){
      float dot0 = acc00[r] + (acc01[r] + acc02[r]);
      float d20  = sqa[0][r] + sqj - 2.0f*dot0;  // sqrt-free, monotone
      if (lj != laba[0][r]){
        if (d20 < mn[0][r]){ mn[0][r]=d20; mj[0][r]=jglob; }
        if (d20 > ap2[0][r] && d20 < th2[0][r] && jglob < sm[0][r]) sm[0][r]=jglob;
      }
      float dot1 = acc10[r] + (acc11[r] + acc12[r]);
      float d21  = sqa[1][r] + sqj - 2.0f*dot1;
      if (lj != laba[1][r]){
        if (d21 < mn[1][r]){ mn[1][r]=d21; mj[1][r]=jglob; }
        if (d21 > ap2[1][r] && d21 < th2[1][r] && jglob < sm[1][r]) sm[1][r]=jglob;
      }
    }
  }
  // reduce across the 16 cols (lane16 butterfly), then across waves, then merge
  #pragma unroll
  for (int g=0; g<2; g++){
    #pragma unroll
    for (int r=0; r<4; r++){
      float v=mn[g][r]; int j=mj[g][r]; int s=sm[g][r];
      #pragma unroll
      for (int off=1; off<16; off<<=1){
        float v2=__shfl_xor(v,off); int j2=__shfl_xor(j,off); int s2=__shfl_xor(s,off);
        if (v2<v || (v2==v && j2<j)){ v=v2; j=j2; }
        s = (s2<s)?s2:s;
      }
      if (lane16==0){
        int ai = g*16 + quad*4 + r;
        rnv[w][ai]=v; rnj[w][ai]=j; rsm[w][ai]=s;
      }
    }
  }
  __syncthreads();
  if (t < 32){
    float V=INFINITY; int J=IMAX; int S=IMAX;
    for (int q=0; q<16; q++){                    // waves ascending = cols ascending
      float v2=rnv[q][t]; int j2=rnj[q][t];
      if (v2<V || (v2==V && j2<J)){ V=v2; J=j2; }
      int s2=rsm[q][t]; S=(s2<S)?s2:S;
    }
    // order-preserving float key: (key32, j) lexicographic == (d2, j) ascending
    unsigned u = __float_as_uint(V);
    unsigned key = (u & 0x80000000u) ? ~u : (u | 0x80000000u);
    unsigned long long k64 = (((unsigned long long)key)<<32) | (unsigned)J;
    atomicMin(&negKey[a0+t], k64);
    if (S != IMAX) atomicMin(&semiJ[a0+t], (unsigned)S);
  }
}

// ------- kernel D: merge halves + exact fp32 loss + deterministic reduce -----
__global__ __launch_bounds__(256) void k_fin2(const float* __restrict__ E,
     const float* __restrict__ apw, const int* __restrict__ hpw,
     const unsigned long long* __restrict__ negKey, const unsigned int* __restrict__ semiJ,
     float* __restrict__ partials, unsigned int* __restrict__ counter,
     float* __restrict__ out){
  __shared__ float lsumS[4], lcntS[4];
  __shared__ float rs[4], rc[4];
  __shared__ int lastFlag;
  int t=threadIdx.x, l=t&63, w=t>>6;
  const float4* E4 = (const float4*)E;
  float lsum=0.f, lcnt=0.f;
  #pragma unroll 1
  for (int i=0;i<4;i++){
    int a = blockIdx.x*16 + w*4 + i;             // wave-uniform anchor
    unsigned long long k64 = negKey[a];
    unsigned Jn = (unsigned)(k64 & 0xFFFFFFFFull);
    unsigned Sn = semiJ[a];
    bool anyneg = (Jn != (unsigned)IMAX);
    int ng = (Sn != 0xFFFFFFFFu) ? (int)Sn : (int)Jn;
    float ap = apw[a];
    bool dov = (ap != -INFINITY) && anyneg;      // valid anchor
    if (dov){
      int hp = hpw[a];
      float4 av = E4[(size_t)a*64 + l];
      float4 pv = E4[(size_t)hp*64 + l];
      float4 nv = E4[(size_t)ng*64 + l];
      float d0=av.x-pv.x+EPSF, d1=av.y-pv.y+EPSF, d2=av.z-pv.z+EPSF, d3=av.w-pv.w+EPSF;
      float sp = fmaf(d0,d0, fmaf(d1,d1, fmaf(d2,d2, d3*d3)));
      float n0=av.x-nv.x+EPSF, n1=av.y-nv.y+EPSF, n2=av.z-nv.z+EPSF, n3=av.w-nv.w+EPSF;
      float sn = fmaf(n0,n0, fmaf(n1,n1, fmaf(n2,n2, n3*n3)));
      #pragma unroll
      for (int off=32; off; off>>=1){ sp += __shfl_xor(sp,off); sn += __shfl_xor(sn,off); }
      lsum += fmaxf(sqrtf(sp)-sqrtf(sn)+MARGINF, 0.0f);
      lcnt += 1.0f;
    }
  }
  if (l==0){ lsumS[w]=lsum; lcntS[w]=lcnt; }
  __syncthreads();
  if (t==0){
    partials[2*blockIdx.x]   = (lsumS[0]+lsumS[1])+(lsumS[2]+lsumS[3]);
    partials[2*blockIdx.x+1] = (lcntS[0]+lcntS[1])+(lcntS[2]+lcntS[3]);
    __threadfence();
    unsigned int old = atomicAdd(counter, 1u);
    lastFlag = (old == gridDim.x - 1) ? 1 : 0;
  }
  __syncthreads();
  if (lastFlag){
    __threadfence();
    float s = partials[2*t], c = partials[2*t+1];   // 256 pairs, fixed order
    #pragma unroll
    for (int off=32; off; off>>=1){ s += __shfl_xor(s,off); c += __shfl_xor(c,off); }
    if (l==0){ rs[w]=s; rc[w]=c; }
    __syncthreads();
    if (t==0){
      float S=(rs[0]+rs[1])+(rs[2]+rs[3]);
      float C=(rc[0]+rc[1])+(rc[2]+rc[3]);
      out[0] = (C>0.0f) ? S/fmaxf(C,1.0f) : 0.0f;
    }
  }
}

// ================= fallback path (small workspace) =================
__global__ __launch_bounds__(256) void k_sq(const float* __restrict__ E, float* __restrict__ sq){
  int i = blockIdx.x*256 + threadIdx.x;
  if (i >= BN) return;
  const float4* r = (const float4*)E + (size_t)i*D4;
  float a0=0.f,a1=0.f,a2=0.f,a3=0.f;
  #pragma unroll
  for (int q=0;q<D4;q+=4){
    a0 = fma4(r[q],r[q],a0);   a1 = fma4(r[q+1],r[q+1],a1);
    a2 = fma4(r[q+2],r[q+2],a2); a3 = fma4(r[q+3],r[q+3],a3);
  }
  sq[i] = (a0+a1)+(a2+a3);
}

__global__ __launch_bounds__(256) void k_pos(const float* __restrict__ E, const int* __restrict__ labels,
                       const float* __restrict__ sq, float* __restrict__ apw,
                       int* __restrict__ hpw, int* __restrict__ anypw){
  __shared__ int members[1024];
  __shared__ float4 mem4[SCAP*65];
  __shared__ int cnts[16][4];
  __shared__ int offs[16][4];
  __shared__ int cntS;
  int t = threadIdx.x, lane = t&63, w = t>>6;
  int c = blockIdx.x >> 2, split = blockIdx.x & 3;
  for (int ch=0; ch<16; ch++){
    bool m = (labels[ch*256 + t] == c);
    unsigned long long mask = __ballot(m);
    if (lane==0) cnts[ch][w] = __popcll(mask);
  }
  __syncthreads();
  if (t==0){
    int run=0;
    for (int ch=0; ch<16; ch++)
      for (int q=0;q<4;q++){ offs[ch][q]=run; run+=cnts[ch][q]; }
    cntS = run;
  }
  __syncthreads();
  int cnt = cntS; if (cnt>1024) cnt=1024;
  for (int ch=0; ch<16; ch++){
    int idx = ch*256 + t;
    bool m = (labels[idx] == c);
    unsigned long long mask = __ballot(m);
    int my = __popcll(mask & ((1ull<<lane)-1ull));
    int pos = offs[ch][w] + my;
    if (m && pos < 1024) members[pos] = idx;
  }
  int S = (cnt < SCAP) ? cnt : SCAP;
  int anyp = (cnt >= 2) ? 1 : 0;
  __syncthreads();
  const float4* E4 = (const float4*)E;
  for (int idx=t; idx<S*64; idx+=256){
    int row = idx>>6, f = idx&63;
    mem4[row*65 + f] = E4[(size_t)members[row]*D4 + f];
  }
  __syncthreads();
  int esplit = split*4 + w;
  int p = lane&3, cand = lane>>2;
  int passes = (cnt+15)>>4;
  for (int mi=esplit; mi<cnt; mi+=16){
    int i = members[mi];
    float sqi = sq[i];
    float4 ai4[16];
    if (mi < S){
      #pragma unroll
      for (int m=0;m<16;m++) ai4[m] = mem4[mi*65 + p + 4*m];
    } else {
      #pragma unroll
      for (int m=0;m<16;m++) ai4[m] = E4[(size_t)i*D4 + p + 4*m];
    }
    float bv = -INFINITY; int bj = IMAX;
    for (int ps=0; ps<passes; ps++){
      int mj = ps*16 + cand;
      if (mj < cnt && mj != mi){
        int j = members[mj];
        float a0v=0.f, a1v=0.f;
        if (mj < S){
          const float4* rj = mem4 + mj*65 + p;
          #pragma unroll
          for (int m=0;m<16;m+=2){ a0v=fma4(ai4[m],rj[4*m],a0v); a1v=fma4(ai4[m+1],rj[4*(m+1)],a1v); }
        } else {
          const float4* rj = E4 + (size_t)j*D4 + p;
          #pragma unroll
          for (int m=0;m<16;m+=2){ a0v=fma4(ai4[m],rj[4*m],a0v); a1v=fma4(ai4[m+1],rj[4*(m+1)],a1v); }
        }
        float acc = a0v+a1v;
        acc += __shfl_xor(acc,1); acc += __shfl_xor(acc,2);
        float d = sqrtf(fmaxf(sqi + sq[j] - 2.0f*acc, 0.0f));
        if (p==0){ if (d > bv || (d==bv && j<bj)){ bv=d; bj=j; } }
      }
    }
    #pragma unroll
    for (int off=32; off; off>>=1){
      float v2=__shfl_xor(bv,off); int j2=__shfl_xor(bj,off);
      if (v2>bv || (v2==bv && j2<bj)){ bv=v2; bj=j2; }
    }
    if (lane==0){
      int J = (bj==IMAX) ? 0 : bj;
      apw[i]=bv; hpw[i]=J; anypw[i]=anyp;
    }
  }
}

__global__ __launch_bounds__(256,2) void k_main(const float* __restrict__ E, const int* __restrict__ labels,
     const float* __restrict__ sq, const float* __restrict__ apw, const int* __restrict__ hpw,
     const int* __restrict__ anypw, float* __restrict__ partials){
  __shared__ float4 At[MI*68 + 4];
  __shared__ float redv[4][MI]; __shared__ int redj[4][MI]; __shared__ int redsm[4][MI];
  __shared__ int finNeg[MI]; __shared__ int finVal[MI];
  __shared__ float redp[4], redn[4];
  int t=threadIdx.x, lane=t&63, w=t>>6;
  int a0 = blockIdx.x * MI;
  const float4* E4 = (const float4*)E;
  for (int idx=t; idx<MI*64; idx+=256){
    int a=idx>>6, q=idx&63, pp=q&3, mm=q>>2;
    At[a*68 + pp*17 + mm] = E4[(size_t)(a0+a)*D4 + q];
  }
  __syncthreads();
  float apv[MI], sqi[MI]; int labi[MI];
  #pragma unroll
  for (int a=0;a<MI;a++){ apv[a]=apw[a0+a]; sqi[a]=sq[a0+a]; labi[a]=labels[a0+a]; }
  float mnv[MI]; int mnj[MI]; int smj[MI];
  #pragma unroll
  for (int a=0;a<MI;a++){ mnv[a]=INFINITY; mnj[a]=0; smj[a]=IMAX; }
  int s = t>>2, p = t&3;
  for (int it=0; it<16; it++){
    int colb = it*256 + 4*s;
    const float4* __restrict__ bp = E4 + (size_t)colb*D4 + p;
    float acc[MI][4];
    #pragma unroll
    for (int a=0;a<MI;a++){
      #pragma unroll
      for (int c2=0;c2<4;c2++) acc[a][c2]=0.0f;
    }
    for (int mg=0; mg<4; mg++){
      float4 b[4][4];
      #pragma unroll
      for (int c2=0;c2<4;c2++){
        #pragma unroll
        for (int m=0;m<4;m++) b[m][c2] = bp[(size_t)c2*D4 + mg*16 + m*4];
      }
      #pragma unroll
      for (int a=0;a<MI;a++){
        float4 a4[4];
        #pragma unroll
        for (int m=0;m<4;m++) a4[m] = At[a*68 + p*17 + mg*4 + m];
        #pragma unroll
        for (int m=0;m<4;m++){
          #pragma unroll
          for (int c2=0;c2<4;c2++) acc[a][c2] = fma4(a4[m], b[m][c2], acc[a][c2]);
        }
      }
    }
    #pragma unroll
    for (int a=0;a<MI;a++){
      #pragma unroll
      for (int c2=0;c2<4;c2++){
        float v = acc[a][c2];
        v += __shfl_xor(v,1); v += __shfl_xor(v,2);
        acc[a][c2] = v;
      }
    }
    #pragma unroll
    for (int c2=0;c2<4;c2++){
      int j = colb + c2;
      int lj = labels[j]; float sqj = sq[j];
      #pragma unroll
      for (int a=0;a<MI;a++){
        float d = sqrtf(fmaxf(sqi[a]+sqj-2.0f*acc[a][c2], 0.0f));
        if (lj != labi[a]){
          if (d < mnv[a]){ mnv[a]=d; mnj[a]=j; }
          if (d > apv[a] && d < apv[a]+MARGINF && j < smj[a]) smj[a]=j;
        }
      }
    }
  }
  #pragma unroll
  for (int a=0;a<MI;a++){
    float v=mnv[a]; int j=mnj[a]; int sm=smj[a];
    #pragma unroll
    for (int off=32; off; off>>=1){
      float v2=__shfl_xor(v,off); int j2=__shfl_xor(j,off); int s2=__shfl_xor(sm,off);
      if (v2<v || (v2==v && j2<j)){ v=v2; j=j2; }
      sm = (s2<sm)?s2:sm;
    }
    if (lane==0){ redv[w][a]=v; redj[w][a]=j; redsm[w][a]=sm; }
  }
  __syncthreads();
  if (t < MI){
    int a=t;
    float V=INFINITY; int J=0; int S=IMAX; bool first=true;
    for (int q=0;q<4;q++){
      float v2=redv[q][a]; int j2=redj[q][a];
      if (first || v2<V || (v2==V && j2<J)){ V=v2; J=j2; first=false; }
      int s2=redsm[q][a]; S=(s2<S)?s2:S;
    }
    bool anyneg = (V < INFINITY);
    finNeg[a] = (S != IMAX) ? S : J;
    finVal[a] = (anypw[a0+a] != 0 && anyneg) ? 1 : 0;
  }
  __syncthreads();
  float lsum=0.0f, lcnt=0.0f;
  for (int a=0;a<MI;a++){
    if (finVal[a]){
      int hp = hpw[a0+a]; int ng = finNeg[a];
      float ai = E[(size_t)(a0+a)*DIM + t];
      float pv = E[(size_t)hp*DIM + t];
      float nv = E[(size_t)ng*DIM + t];
      float dp = ai - pv + EPSF; float dn = ai - nv + EPSF;
      float sp = dp*dp, sn = dn*dn;
      #pragma unroll
      for (int off=32; off; off>>=1){ sp += __shfl_xor(sp,off); sn += __shfl_xor(sn,off); }
      if (lane==0){ redp[w]=sp; redn[w]=sn; }
    }
    __syncthreads();
    if (finVal[a] && t==0){
      float SP=(redp[0]+redp[1])+(redp[2]+redp[3]);
      float SN=(redn[0]+redn[1])+(redn[2]+redn[3]);
      lsum += fmaxf(sqrtf(SP)-sqrtf(SN)+MARGINF, 0.0f);
      lcnt += 1.0f;
    }
    __syncthreads();
  }
  if (t==0){ partials[2*blockIdx.x]=lsum; partials[2*blockIdx.x+1]=lcnt; }
}

__global__ __launch_bounds__(256) void k_fin(const float* __restrict__ partials, float* __restrict__ out, int nb){
  __shared__ float rs[4], rc[4];
  int t=threadIdx.x, lane=t&63, w=t>>6;
  float s=0.f, c=0.f;
  for (int q=t;q<nb;q+=256){ s+=partials[2*q]; c+=partials[2*q+1]; }
  #pragma unroll
  for (int off=32; off; off>>=1){ s+=__shfl_xor(s,off); c+=__shfl_xor(c,off); }
  if (lane==0){ rs[w]=s; rc[w]=c; }
  __syncthreads();
  if (t==0){
    float S=(rs[0]+rs[1])+(rs[2]+rs[3]);
    float C=(rc[0]+rc[1])+(rc[2]+rc[3]);
    out[0] = (C>0.0f) ? S/fmaxf(C,1.0f) : 0.0f;
  }
}

extern "C" void kernel_launch(void* const* d_in, const int* in_sizes, int n_in,
                              void* d_out, int out_size, void* d_ws, size_t ws_size,
                              hipStream_t stream) {
  const float* E      = (const float*)d_in[0];   // 4096x256 fp32
  const int*   labels = (const int*)d_in[1];     // 4096 int32
  float* out = (float*)d_out;

  float* sqw      = (float*)d_ws;          // 4096 f          @ 0
  float* apw      = sqw + BN;              // 4096 f          @ 16K
  int*   hpw      = (int*)(apw + BN);      // 4096 i          @ 32K
  int*   anypw    = hpw + BN;              // 4096 i (fallback only) @ 48K
  float* partials = (float*)(anypw + BN);  // 1024 f          @ 64K
  unsigned int* counter = (unsigned int*)(partials + 1024);   // @ 68K
  unsigned long long* negKey = (unsigned long long*)((char*)d_ws + 72*1024);  // 32 KB
  unsigned int*       semiJ  = (unsigned int*)((char*)d_ws + 104*1024);       // 16 KB
  unsigned short* EhiT = (unsigned short*)((char*)d_ws + 131072);       // 2 MB (tiled)
  unsigned short* EloT = EhiT + (size_t)BN*DIM;                         // 2 MB (tiled)
  bool big = ws_size >= (size_t)(131072 + 4*1024*1024);

  if (big){
    k_pre2<<<256,  256,  0, stream>>>(E, EhiT, EloT, sqw, counter);
    k_posm<<<1024, 256,  0, stream>>>(E, labels, sqw, apw, hpw, negKey, semiJ);
    k_negm<<<256,  1024, 0, stream>>>(EhiT, EloT, labels, sqw, apw, negKey, semiJ);
    k_fin2<<<256,  256,  0, stream>>>(E, apw, hpw, negKey, semiJ, partials, counter, out);
  } else {
    k_sq  <<<BN/256, 256, 0, stream>>>(E, sqw);
    k_pos <<<256,    256, 0, stream>>>(E, labels, sqw, apw, hpw, anypw);
    k_main<<<BN/MI,  256, 0, stream>>>(E, labels, sqw, apw, hpw, anypw, partials);
    k_fin <<<1,      256, 0, stream>>>(partials, out, BN/MI);
  }
}